// Round 4
// baseline (787.878 us; speedup 1.0000x reference)
//
#include <hip/hip_runtime.h>
#include <cmath>

// ---------- problem dims (fixed) ----------
#define BB 4
#define PP 1024
#define DD 1024
#define HH 16
#define DHH 64
#define MLPD 4096

typedef __bf16 bf16x8 __attribute__((ext_vector_type(8)));
typedef float f32x4 __attribute__((ext_vector_type(4)));
typedef short short8 __attribute__((ext_vector_type(8)));

__device__ __forceinline__ unsigned short f2b(float f) {
  union { float f; unsigned int u; } x; x.f = f;
  unsigned int r = x.u + 0x7fffu + ((x.u >> 16) & 1u);
  return (unsigned short)(r >> 16);
}

__device__ __forceinline__ f32x4 mfma16(short8 a, short8 b, f32x4 c) {
  return __builtin_amdgcn_mfma_f32_16x16x32_bf16(
      __builtin_bit_cast(bf16x8, a), __builtin_bit_cast(bf16x8, b), c, 0, 0, 0);
}

// ---------- LayerNorm: fp32 [rows][1024] -> bf16 [rows][1024] ----------
__global__ __launch_bounds__(256)
void ln_kernel(const float* __restrict__ in, const float* __restrict__ g,
               const float* __restrict__ bta, unsigned short* __restrict__ out) {
  int row = blockIdx.x;
  int t = threadIdx.x;
  const float* x = in + (size_t)row * DD;
  float v0 = x[t], v1 = x[t + 256], v2 = x[t + 512], v3 = x[t + 768];
  float s = v0 + v1 + v2 + v3;
  float ss = v0 * v0 + v1 * v1 + v2 * v2 + v3 * v3;
#pragma unroll
  for (int m = 1; m < 64; m <<= 1) { s += __shfl_xor(s, m); ss += __shfl_xor(ss, m); }
  __shared__ float red[8];
  int wave = t >> 6;
  if ((t & 63) == 0) { red[wave] = s; red[4 + wave] = ss; }
  __syncthreads();
  s = red[0] + red[1] + red[2] + red[3];
  ss = red[4] + red[5] + red[6] + red[7];
  float mu = s * (1.f / DD);
  float var = ss * (1.f / DD) - mu * mu;
  float r = rsqrtf(var + 1e-5f);
  unsigned short* o = out + (size_t)row * DD;
  o[t]       = f2b((v0 - mu) * r * g[t]       + bta[t]);
  o[t + 256] = f2b((v1 - mu) * r * g[t + 256] + bta[t + 256]);
  o[t + 512] = f2b((v2 - mu) * r * g[t + 512] + bta[t + 512]);
  o[t + 768] = f2b((v3 - mu) * r * g[t + 768] + bta[t + 768]);
}

// ---------- GEMM: C[M,N] = A(bf16,[M,K]) * B(f32,[K,N]) + bias, epilogues ----------
// EPI 0: split q/k/v -> bf16 [B,H,P,DH]
// EPI 1: out fp32 = acc + bias + resid
// EPI 2: out bf16 = gelu(acc + bias)
template <int EPI>
__global__ __launch_bounds__(256)
void gemm_kernel(const unsigned short* __restrict__ A, const float* __restrict__ Bw,
                 const float* __restrict__ bias, const float* __restrict__ resid,
                 float* __restrict__ outF, unsigned short* __restrict__ outQ,
                 unsigned short* __restrict__ outK, unsigned short* __restrict__ outV,
                 unsigned short* __restrict__ outB, int M, int N, int K) {
  __shared__ unsigned short Asl[128][40];  // [row][k], +8 pad
  __shared__ unsigned short Bsl[128][40];  // [col][k] (transposed), +8 pad
  int t = threadIdx.x;
  int wave = t >> 6, lane = t & 63;
  int wm = wave >> 1, wn = wave & 1;
  int lr = lane & 15, lg = lane >> 4;

  int bm0 = blockIdx.y * 128, bn0 = blockIdx.x * 128;

  f32x4 zero = {0.f, 0.f, 0.f, 0.f};
  f32x4 acc[4][4];
#pragma unroll
  for (int i = 0; i < 4; ++i)
#pragma unroll
    for (int j = 0; j < 4; ++j) acc[i][j] = zero;

  int ar = t >> 2, ac = (t & 3) * 8;   // A staging
  int br = t >> 5, bc = (t & 31) * 4;  // B staging

  for (int k0 = 0; k0 < K; k0 += 32) {
    __syncthreads();
#pragma unroll
    for (int p = 0; p < 2; ++p) {  // A tile 128x32 bf16
      int r = ar + p * 64;
      *(short8*)&Asl[r][ac] = *(const short8*)&A[(size_t)(bm0 + r) * K + k0 + ac];
    }
#pragma unroll
    for (int p = 0; p < 4; ++p) {  // B tile 32x128 f32 -> bf16 transposed
      int r = br + p * 8;
      const float4 v = *reinterpret_cast<const float4*>(&Bw[(size_t)(k0 + r) * N + bn0 + bc]);
      Bsl[bc + 0][r] = f2b(v.x);
      Bsl[bc + 1][r] = f2b(v.y);
      Bsl[bc + 2][r] = f2b(v.z);
      Bsl[bc + 3][r] = f2b(v.w);
    }
    __syncthreads();
    short8 af[4], bf[4];
#pragma unroll
    for (int i = 0; i < 4; ++i) af[i] = *(const short8*)&Asl[wm * 64 + i * 16 + lr][lg * 8];
#pragma unroll
    for (int i = 0; i < 4; ++i) bf[i] = *(const short8*)&Bsl[wn * 64 + i * 16 + lr][lg * 8];
#pragma unroll
    for (int mi = 0; mi < 4; ++mi)
#pragma unroll
      for (int ni = 0; ni < 4; ++ni) acc[mi][ni] = mfma16(af[mi], bf[ni], acc[mi][ni]);
  }

#pragma unroll
  for (int mi = 0; mi < 4; ++mi)
#pragma unroll
    for (int ni = 0; ni < 4; ++ni) {
      int r0 = bm0 + wm * 64 + mi * 16 + lg * 4;
      int c = bn0 + wn * 64 + ni * 16 + lr;
      float bval = bias[c];
#pragma unroll
      for (int j = 0; j < 4; ++j) {
        float v = acc[mi][ni][j] + bval;
        int row = r0 + j;
        size_t idx = (size_t)row * N + c;
        if constexpr (EPI == 1) {
          outF[idx] = v + resid[idx];
        } else if constexpr (EPI == 2) {
          outB[idx] = f2b(0.5f * v * (1.f + erff(v * 0.70710678f)));
        } else {  // QKV split
          int which = c >> 10, rem = c & 1023;
          int h = rem >> 6, dh = rem & 63;
          int b = row >> 10, p = row & 1023;
          unsigned short* dst = (which == 0) ? outQ : (which == 1) ? outK : outV;
          dst[(((size_t)b * HH + h) * PP + p) * DHH + dh] = f2b(v);
        }
      }
    }
}

// ---------- Flash attention: q,k,v bf16 [B*H][P][64] -> o bf16 [B*P][1024] ----------
__global__ __launch_bounds__(256)
void attn_kernel(const unsigned short* __restrict__ Qg, const unsigned short* __restrict__ Kg,
                 const unsigned short* __restrict__ Vg, unsigned short* __restrict__ Og) {
  int bh = blockIdx.x;  // b*H + h
  int qb = blockIdx.y;  // q block of 64
  int t = threadIdx.x;
  int wave = t >> 6, lane = t & 63;
  int lr = lane & 15, lg = lane >> 4;

  __shared__ unsigned short Kl[64][72];      // [kv][dh] +8 pad
  __shared__ unsigned short Vt[64][72];      // [dh][kv] +8 pad (transposed)
  __shared__ unsigned short Pl[4][16][72];   // per-wave P

  const unsigned short* qrow = Qg + ((size_t)bh * PP + qb * 64 + wave * 16 + lr) * DHH;
  short8 qf0 = *(const short8*)(qrow + lg * 8);
  short8 qf1 = *(const short8*)(qrow + 32 + lg * 8);

  f32x4 zero = {0.f, 0.f, 0.f, 0.f};
  f32x4 accO[4];
#pragma unroll
  for (int i = 0; i < 4; ++i) accO[i] = zero;
  float m_run[4], l_run[4];
#pragma unroll
  for (int j = 0; j < 4; ++j) { m_run[j] = -1e30f; l_run[j] = 0.f; }

  const unsigned short* Kbase = Kg + (size_t)bh * PP * DHH;
  const unsigned short* Vbase = Vg + (size_t)bh * PP * DHH;

  int kvr = t >> 3, chc = (t & 7) * 8;

  for (int kb = 0; kb < PP / 64; ++kb) {
    __syncthreads();
#pragma unroll
    for (int p = 0; p < 2; ++p) {
      int r = kvr + p * 32;
      short8 k8 = *(const short8*)(Kbase + (size_t)(kb * 64 + r) * DHH + chc);
      *(short8*)&Kl[r][chc] = k8;
      short8 v8 = *(const short8*)(Vbase + (size_t)(kb * 64 + r) * DHH + chc);
#pragma unroll
      for (int i = 0; i < 8; ++i) Vt[chc + i][r] = (unsigned short)v8[i];
    }
    __syncthreads();

    // S = Q K^T  (scaled)
    f32x4 s[4];
#pragma unroll
    for (int ni = 0; ni < 4; ++ni) {
      s[ni] = zero;
      short8 kf0 = *(const short8*)&Kl[ni * 16 + lr][lg * 8];
      short8 kf1 = *(const short8*)&Kl[ni * 16 + lr][32 + lg * 8];
      s[ni] = mfma16(qf0, kf0, s[ni]);
      s[ni] = mfma16(qf1, kf1, s[ni]);
    }
#pragma unroll
    for (int ni = 0; ni < 4; ++ni)
#pragma unroll
      for (int j = 0; j < 4; ++j) s[ni][j] *= 0.125f;  // DH^-0.5

    // online softmax, rows are (lg*4+j), row spread over 16 lanes x 4 ni
#pragma unroll
    for (int j = 0; j < 4; ++j) {
      float mt = fmaxf(fmaxf(s[0][j], s[1][j]), fmaxf(s[2][j], s[3][j]));
      mt = fmaxf(mt, __shfl_xor(mt, 1));
      mt = fmaxf(mt, __shfl_xor(mt, 2));
      mt = fmaxf(mt, __shfl_xor(mt, 4));
      mt = fmaxf(mt, __shfl_xor(mt, 8));
      float mn = fmaxf(m_run[j], mt);
      float sc = __expf(m_run[j] - mn);
      m_run[j] = mn;
      float ps = 0.f;
#pragma unroll
      for (int ni = 0; ni < 4; ++ni) {
        float p = __expf(s[ni][j] - mn);
        s[ni][j] = p;
        ps += p;
      }
      l_run[j] = l_run[j] * sc + ps;
#pragma unroll
      for (int ni = 0; ni < 4; ++ni) accO[ni][j] *= sc;
    }

    // P -> LDS (C layout -> A layout re-fragmentation)
#pragma unroll
    for (int ni = 0; ni < 4; ++ni)
#pragma unroll
      for (int j = 0; j < 4; ++j) Pl[wave][lg * 4 + j][ni * 16 + lr] = f2b(s[ni][j]);
    __syncthreads();

    // O += P V
    short8 pf0 = *(const short8*)&Pl[wave][lr][lg * 8];
    short8 pf1 = *(const short8*)&Pl[wave][lr][32 + lg * 8];
#pragma unroll
    for (int ni = 0; ni < 4; ++ni) {
      short8 vf0 = *(const short8*)&Vt[ni * 16 + lr][lg * 8];
      short8 vf1 = *(const short8*)&Vt[ni * 16 + lr][32 + lg * 8];
      accO[ni] = mfma16(pf0, vf0, accO[ni]);
      accO[ni] = mfma16(pf1, vf1, accO[ni]);
    }
  }

  // normalize + store, o layout [B*P][H*DH]
#pragma unroll
  for (int j = 0; j < 4; ++j) {
    float l = l_run[j];
    l += __shfl_xor(l, 1);
    l += __shfl_xor(l, 2);
    l += __shfl_xor(l, 4);
    l += __shfl_xor(l, 8);
    float inv = 1.f / l;
#pragma unroll
    for (int ni = 0; ni < 4; ++ni) accO[ni][j] *= inv;
  }
  size_t token = (size_t)(bh >> 4) * PP + qb * 64 + wave * 16;
  int h = bh & 15;
#pragma unroll
  for (int ni = 0; ni < 4; ++ni)
#pragma unroll
    for (int j = 0; j < 4; ++j)
      Og[(token + lg * 4 + j) * DD + h * DHH + ni * 16 + lr] = f2b(accO[ni][j]);
}

// ---------- launch ----------
extern "C" void kernel_launch(void* const* d_in, const int* in_sizes, int n_in,
                              void* d_out, int out_size, void* d_ws, size_t ws_size,
                              hipStream_t stream) {
  const float* x    = (const float*)d_in[0];
  const float* ln1g = (const float*)d_in[1];
  const float* ln1b = (const float*)d_in[2];
  const float* Wqkv = (const float*)d_in[3];
  const float* bqkv = (const float*)d_in[4];
  const float* Wo   = (const float*)d_in[5];
  const float* bo   = (const float*)d_in[6];
  const float* ln2g = (const float*)d_in[7];
  const float* ln2b = (const float*)d_in[8];
  const float* W1   = (const float*)d_in[9];
  const float* b1   = (const float*)d_in[10];
  const float* W2   = (const float*)d_in[11];
  const float* b2   = (const float*)d_in[12];
  float* out = (float*)d_out;

  char* ws = (char*)d_ws;
  unsigned short* xn = (unsigned short*)(ws);                    // 8MB  LN1 out
  unsigned short* qb = (unsigned short*)(ws + (8ull << 20));     // 8MB
  unsigned short* kb = (unsigned short*)(ws + (16ull << 20));    // 8MB
  unsigned short* vb = (unsigned short*)(ws + (24ull << 20));    // 8MB
  unsigned short* ob = (unsigned short*)(ws + (32ull << 20));    // 8MB  attn out
  float*          x2 = (float*)(ws + (40ull << 20));             // 16MB post-attn resid
  unsigned short* hn = (unsigned short*)(ws + (56ull << 20));    // 8MB  LN2 out
  unsigned short* h1 = (unsigned short*)(ws + (64ull << 20));    // 32MB MLP hidden

  const int M = BB * PP;  // 4096

  ln_kernel<<<M, 256, 0, stream>>>(x, ln1g, ln1b, xn);
  gemm_kernel<0><<<dim3(3 * DD / 128, M / 128), 256, 0, stream>>>(
      xn, Wqkv, bqkv, nullptr, nullptr, qb, kb, vb, nullptr, M, 3 * DD, DD);
  attn_kernel<<<dim3(BB * HH, PP / 64), 256, 0, stream>>>(qb, kb, vb, ob);
  gemm_kernel<1><<<dim3(DD / 128, M / 128), 256, 0, stream>>>(
      ob, Wo, bo, x, x2, nullptr, nullptr, nullptr, nullptr, M, DD, DD);
  ln_kernel<<<M, 256, 0, stream>>>(x2, ln2g, ln2b, hn);
  gemm_kernel<2><<<dim3(MLPD / 128, M / 128), 256, 0, stream>>>(
      hn, W1, b1, nullptr, nullptr, nullptr, nullptr, nullptr, h1, M, MLPD, DD);
  gemm_kernel<1><<<dim3(DD / 128, M / 128), 256, 0, stream>>>(
      h1, W2, b2, x2, out, nullptr, nullptr, nullptr, nullptr, M, DD, MLPD);
}

// Round 7
// 436.669 us; speedup vs baseline: 1.8043x; 1.8043x over previous
//
#include <hip/hip_runtime.h>
#include <cmath>

// ---------- problem dims (fixed) ----------
#define BB 4
#define PP 1024
#define DD 1024
#define HH 16
#define DHH 64
#define MLPD 4096

typedef __bf16 bf16x8 __attribute__((ext_vector_type(8)));
typedef float f32x4 __attribute__((ext_vector_type(4)));
typedef short short8 __attribute__((ext_vector_type(8)));

__device__ __forceinline__ unsigned short f2b(float f) {
  union { float f; unsigned int u; } x; x.f = f;
  unsigned int r = x.u + 0x7fffu + ((x.u >> 16) & 1u);
  return (unsigned short)(r >> 16);
}

__device__ __forceinline__ f32x4 mfma16(short8 a, short8 b, f32x4 c) {
  return __builtin_amdgcn_mfma_f32_16x16x32_bf16(
      __builtin_bit_cast(bf16x8, a), __builtin_bit_cast(bf16x8, b), c, 0, 0, 0);
}

__device__ __forceinline__ void gload_lds16(const unsigned short* g, unsigned short* l) {
  __builtin_amdgcn_global_load_lds(
      (const __attribute__((address_space(1))) void*)g,
      (__attribute__((address_space(3))) void*)l, 16, 0, 0);
}

// ---------- LayerNorm: fp32 [rows][1024] -> bf16 [rows][1024] ----------
__global__ __launch_bounds__(256)
void ln_kernel(const float* __restrict__ in, const float* __restrict__ g,
               const float* __restrict__ bta, unsigned short* __restrict__ out) {
  int row = blockIdx.x;
  int t = threadIdx.x;
  const float* x = in + (size_t)row * DD;
  float v0 = x[t], v1 = x[t + 256], v2 = x[t + 512], v3 = x[t + 768];
  float s = v0 + v1 + v2 + v3;
  float ss = v0 * v0 + v1 * v1 + v2 * v2 + v3 * v3;
#pragma unroll
  for (int m = 1; m < 64; m <<= 1) { s += __shfl_xor(s, m); ss += __shfl_xor(ss, m); }
  __shared__ float red[8];
  int wave = t >> 6;
  if ((t & 63) == 0) { red[wave] = s; red[4 + wave] = ss; }
  __syncthreads();
  s = red[0] + red[1] + red[2] + red[3];
  ss = red[4] + red[5] + red[6] + red[7];
  float mu = s * (1.f / DD);
  float var = ss * (1.f / DD) - mu * mu;
  float r = rsqrtf(var + 1e-5f);
  unsigned short* o = out + (size_t)row * DD;
  o[t]       = f2b((v0 - mu) * r * g[t]       + bta[t]);
  o[t + 256] = f2b((v1 - mu) * r * g[t + 256] + bta[t + 256]);
  o[t + 512] = f2b((v2 - mu) * r * g[t + 512] + bta[t + 512]);
  o[t + 768] = f2b((v3 - mu) * r * g[t + 768] + bta[t + 768]);
}

// ---------- Transpose+cast: W f32 [K][N] -> Wt bf16 [N][K], 64x64 tiles ----------
__global__ __launch_bounds__(256)
void tcast_kernel(const float* __restrict__ W, unsigned short* __restrict__ Wt,
                  int K, int N) {
  __shared__ float Tl[64][65];
  int k0 = blockIdx.y * 64, n0 = blockIdx.x * 64;
  int t = threadIdx.x;
  int rr = t >> 4, cc = (t & 15) * 4;
#pragma unroll
  for (int p = 0; p < 4; ++p) {
    const float4 v = *(const float4*)&W[(size_t)(k0 + rr + p * 16) * N + n0 + cc];
    Tl[rr + p * 16][cc + 0] = v.x;
    Tl[rr + p * 16][cc + 1] = v.y;
    Tl[rr + p * 16][cc + 2] = v.z;
    Tl[rr + p * 16][cc + 3] = v.w;
  }
  __syncthreads();
  int wr = t >> 3, wc = (t & 7) * 8;
#pragma unroll
  for (int p = 0; p < 2; ++p) {
    int n = wr + p * 32;
    short8 o;
#pragma unroll
    for (int i = 0; i < 8; ++i) o[i] = (short)f2b(Tl[wc + i][n]);
    *(short8*)&Wt[(size_t)(n0 + n) * K + k0 + wc] = o;
  }
}

// ---------- GEMM: C[M,N] = A(bf16,[M,K]) * Bt(bf16,[N][K])^T + bias ----------
// m97 structure: [rows][32] linear LDS, global_load_lds width 16, 2-barrier K-step.
// EPI 0: split q/k/v -> bf16 [B,H,P,DH];  EPI 1: fp32 = acc+bias+resid;  EPI 2: bf16 = gelu(acc+bias)
template <int EPI, int BM, int BN>
__global__ __launch_bounds__(256)
void gemm_bt(const unsigned short* __restrict__ A, const unsigned short* __restrict__ Bt,
             const float* __restrict__ bias, const float* __restrict__ resid,
             float* __restrict__ outF, unsigned short* __restrict__ outB,
             unsigned short* __restrict__ outQ, unsigned short* __restrict__ outK,
             unsigned short* __restrict__ outV, int M, int N, int K) {
  constexpr int WM = BM / 2, WN = BN / 2, FM = WM / 16, FN = WN / 16;
  __shared__ unsigned short As[BM * 32];
  __shared__ unsigned short Bs[BN * 32];
  int t = threadIdx.x;
  int wave = t >> 6, lane = t & 63;
  int wm = wave >> 1, wn = wave & 1;
  int lr = lane & 15, lg = lane >> 4;
  int bm0 = blockIdx.y * BM, bn0 = blockIdx.x * BN;

  int srow = lane >> 2;          // row within 16-row chunk
  int skof = (lane & 3) * 8;     // k offset (shorts)

  f32x4 acc[FM][FN];
#pragma unroll
  for (int i = 0; i < FM; ++i)
#pragma unroll
    for (int j = 0; j < FN; ++j) acc[i][j] = (f32x4){0.f, 0.f, 0.f, 0.f};

  for (int k0 = 0; k0 < K; k0 += 32) {
    __syncthreads();
#pragma unroll
    for (int i = 0; i < BM / 64; ++i) {  // A chunks: wave-uniform LDS base, lane*16B linear
      int ch = wave + i * 4;
      gload_lds16(&A[(size_t)(bm0 + ch * 16 + srow) * K + k0 + skof], &As[ch * 512]);
    }
#pragma unroll
    for (int i = 0; i < BN / 64; ++i) {
      int ch = wave + i * 4;
      gload_lds16(&Bt[(size_t)(bn0 + ch * 16 + srow) * K + k0 + skof], &Bs[ch * 512]);
    }
    __syncthreads();
    short8 af[FM], bf[FN];
#pragma unroll
    for (int i = 0; i < FM; ++i) af[i] = *(const short8*)&As[(wm * WM + i * 16 + lr) * 32 + lg * 8];
#pragma unroll
    for (int i = 0; i < FN; ++i) bf[i] = *(const short8*)&Bs[(wn * WN + i * 16 + lr) * 32 + lg * 8];
#pragma unroll
    for (int mi = 0; mi < FM; ++mi)
#pragma unroll
      for (int ni = 0; ni < FN; ++ni) acc[mi][ni] = mfma16(af[mi], bf[ni], acc[mi][ni]);
  }

#pragma unroll
  for (int mi = 0; mi < FM; ++mi)
#pragma unroll
    for (int ni = 0; ni < FN; ++ni) {
      int r0 = bm0 + wm * WM + mi * 16 + lg * 4;
      int c = bn0 + wn * WN + ni * 16 + lr;
      float bval = bias[c];
#pragma unroll
      for (int j = 0; j < 4; ++j) {
        float v = acc[mi][ni][j] + bval;
        int row = r0 + j;
        size_t idx = (size_t)row * N + c;
        if constexpr (EPI == 1) {
          outF[idx] = v + resid[idx];
        } else if constexpr (EPI == 2) {
          outB[idx] = f2b(0.5f * v * (1.f + erff(v * 0.70710678f)));
        } else {  // QKV split
          int which = c >> 10, rem = c & 1023;
          int h = rem >> 6, dh = rem & 63;
          int b = row >> 10, p = row & 1023;
          unsigned short* dst = (which == 0) ? outQ : (which == 1) ? outK : outV;
          dst[(((size_t)b * HH + h) * PP + p) * DHH + dh] = f2b(v);
        }
      }
    }
}

// ---------- Flash attention: q,k,v bf16 [B*H][P][64] -> o bf16 [B*P][1024] ----------
__global__ __launch_bounds__(256)
void attn_kernel(const unsigned short* __restrict__ Qg, const unsigned short* __restrict__ Kg,
                 const unsigned short* __restrict__ Vg, unsigned short* __restrict__ Og) {
  int bh = blockIdx.x;  // b*H + h
  int qb = blockIdx.y;  // q block of 64
  int t = threadIdx.x;
  int wave = t >> 6, lane = t & 63;
  int lr = lane & 15, lg = lane >> 4;

  __shared__ unsigned short Kl[64][72];
  __shared__ unsigned short Vt[64][72];
  __shared__ unsigned short Pl[4][16][72];

  const unsigned short* qrow = Qg + ((size_t)bh * PP + qb * 64 + wave * 16 + lr) * DHH;
  short8 qf0 = *(const short8*)(qrow + lg * 8);
  short8 qf1 = *(const short8*)(qrow + 32 + lg * 8);

  f32x4 zero = {0.f, 0.f, 0.f, 0.f};
  f32x4 accO[4];
#pragma unroll
  for (int i = 0; i < 4; ++i) accO[i] = zero;
  float m_run[4], l_run[4];
#pragma unroll
  for (int j = 0; j < 4; ++j) { m_run[j] = -1e30f; l_run[j] = 0.f; }

  const unsigned short* Kbase = Kg + (size_t)bh * PP * DHH;
  const unsigned short* Vbase = Vg + (size_t)bh * PP * DHH;

  int kvr = t >> 3, chc = (t & 7) * 8;

  for (int kb = 0; kb < PP / 64; ++kb) {
    __syncthreads();
#pragma unroll
    for (int p = 0; p < 2; ++p) {
      int r = kvr + p * 32;
      short8 k8 = *(const short8*)(Kbase + (size_t)(kb * 64 + r) * DHH + chc);
      *(short8*)&Kl[r][chc] = k8;
      short8 v8 = *(const short8*)(Vbase + (size_t)(kb * 64 + r) * DHH + chc);
#pragma unroll
      for (int i = 0; i < 8; ++i) Vt[chc + i][r] = (unsigned short)v8[i];
    }
    __syncthreads();

    f32x4 s[4];
#pragma unroll
    for (int ni = 0; ni < 4; ++ni) {
      s[ni] = zero;
      short8 kf0 = *(const short8*)&Kl[ni * 16 + lr][lg * 8];
      short8 kf1 = *(const short8*)&Kl[ni * 16 + lr][32 + lg * 8];
      s[ni] = mfma16(qf0, kf0, s[ni]);
      s[ni] = mfma16(qf1, kf1, s[ni]);
    }
#pragma unroll
    for (int ni = 0; ni < 4; ++ni)
#pragma unroll
      for (int j = 0; j < 4; ++j) s[ni][j] *= 0.125f;

#pragma unroll
    for (int j = 0; j < 4; ++j) {
      float mt = fmaxf(fmaxf(s[0][j], s[1][j]), fmaxf(s[2][j], s[3][j]));
      mt = fmaxf(mt, __shfl_xor(mt, 1));
      mt = fmaxf(mt, __shfl_xor(mt, 2));
      mt = fmaxf(mt, __shfl_xor(mt, 4));
      mt = fmaxf(mt, __shfl_xor(mt, 8));
      float mn = fmaxf(m_run[j], mt);
      float sc = __expf(m_run[j] - mn);
      m_run[j] = mn;
      float ps = 0.f;
#pragma unroll
      for (int ni = 0; ni < 4; ++ni) {
        float p = __expf(s[ni][j] - mn);
        s[ni][j] = p;
        ps += p;
      }
      l_run[j] = l_run[j] * sc + ps;
#pragma unroll
      for (int ni = 0; ni < 4; ++ni) accO[ni][j] *= sc;
    }

#pragma unroll
    for (int ni = 0; ni < 4; ++ni)
#pragma unroll
      for (int j = 0; j < 4; ++j) Pl[wave][lg * 4 + j][ni * 16 + lr] = f2b(s[ni][j]);
    __syncthreads();

    short8 pf0 = *(const short8*)&Pl[wave][lr][lg * 8];
    short8 pf1 = *(const short8*)&Pl[wave][lr][32 + lg * 8];
#pragma unroll
    for (int ni = 0; ni < 4; ++ni) {
      short8 vf0 = *(const short8*)&Vt[ni * 16 + lr][lg * 8];
      short8 vf1 = *(const short8*)&Vt[ni * 16 + lr][32 + lg * 8];
      accO[ni] = mfma16(pf0, vf0, accO[ni]);
      accO[ni] = mfma16(pf1, vf1, accO[ni]);
    }
  }

#pragma unroll
  for (int j = 0; j < 4; ++j) {
    float l = l_run[j];
    l += __shfl_xor(l, 1);
    l += __shfl_xor(l, 2);
    l += __shfl_xor(l, 4);
    l += __shfl_xor(l, 8);
    float inv = 1.f / l;
#pragma unroll
    for (int ni = 0; ni < 4; ++ni) accO[ni][j] *= inv;
  }
  size_t token = (size_t)(bh >> 4) * PP + qb * 64 + wave * 16;
  int h = bh & 15;
#pragma unroll
  for (int ni = 0; ni < 4; ++ni)
#pragma unroll
    for (int j = 0; j < 4; ++j)
      Og[(token + lg * 4 + j) * DD + h * DHH + ni * 16 + lr] = f2b(accO[ni][j]);
}

// ---------- launch ----------
extern "C" void kernel_launch(void* const* d_in, const int* in_sizes, int n_in,
                              void* d_out, int out_size, void* d_ws, size_t ws_size,
                              hipStream_t stream) {
  const float* x    = (const float*)d_in[0];
  const float* ln1g = (const float*)d_in[1];
  const float* ln1b = (const float*)d_in[2];
  const float* Wqkv = (const float*)d_in[3];
  const float* bqkv = (const float*)d_in[4];
  const float* Wo   = (const float*)d_in[5];
  const float* bo   = (const float*)d_in[6];
  const float* ln2g = (const float*)d_in[7];
  const float* ln2b = (const float*)d_in[8];
  const float* W1   = (const float*)d_in[9];
  const float* b1   = (const float*)d_in[10];
  const float* W2   = (const float*)d_in[11];
  const float* b2   = (const float*)d_in[12];
  float* out = (float*)d_out;

  char* ws = (char*)d_ws;
  // layout (MB): [0,8) xn then hn  | [8,40) q/k/v/ob then h1 | [40,56) x2 |
  //              [56,62) WqkvT | [62,64) WoT | [64,72) W1T | [72,80) W2T
  unsigned short* xn   = (unsigned short*)(ws);
  unsigned short* hn   = (unsigned short*)(ws);                  // alias: xn dead after QKV
  unsigned short* qb   = (unsigned short*)(ws + (8ull << 20));
  unsigned short* kb   = (unsigned short*)(ws + (16ull << 20));
  unsigned short* vb   = (unsigned short*)(ws + (24ull << 20));
  unsigned short* ob   = (unsigned short*)(ws + (32ull << 20));
  unsigned short* h1   = (unsigned short*)(ws + (8ull << 20));   // alias: qkv+ob dead after proj
  float*          x2   = (float*)(ws + (40ull << 20));
  unsigned short* WqkvT= (unsigned short*)(ws + (56ull << 20));
  unsigned short* WoT  = (unsigned short*)(ws + (62ull << 20));
  unsigned short* W1T  = (unsigned short*)(ws + (64ull << 20));
  unsigned short* W2T  = (unsigned short*)(ws + (72ull << 20));

  const int M = BB * PP;  // 4096

  // one-time weight precast+transpose (graph-replayed each call; ~20us total)
  tcast_kernel<<<dim3(3 * DD / 64, DD / 64), 256, 0, stream>>>(Wqkv, WqkvT, DD, 3 * DD);
  tcast_kernel<<<dim3(DD / 64, DD / 64), 256, 0, stream>>>(Wo, WoT, DD, DD);
  tcast_kernel<<<dim3(MLPD / 64, DD / 64), 256, 0, stream>>>(W1, W1T, DD, MLPD);
  tcast_kernel<<<dim3(DD / 64, MLPD / 64), 256, 0, stream>>>(W2, W2T, MLPD, DD);

  ln_kernel<<<M, 256, 0, stream>>>(x, ln1g, ln1b, xn);
  gemm_bt<0, 128, 128><<<dim3(3 * DD / 128, M / 128), 256, 0, stream>>>(
      xn, WqkvT, bqkv, nullptr, nullptr, nullptr, qb, kb, vb, M, 3 * DD, DD);
  attn_kernel<<<dim3(BB * HH, PP / 64), 256, 0, stream>>>(qb, kb, vb, ob);
  gemm_bt<1, 64, 128><<<dim3(DD / 128, M / 64), 256, 0, stream>>>(
      ob, WoT, bo, x, x2, nullptr, nullptr, nullptr, nullptr, M, DD, DD);
  ln_kernel<<<M, 256, 0, stream>>>(x2, ln2g, ln2b, hn);
  gemm_bt<2, 128, 128><<<dim3(MLPD / 128, M / 128), 256, 0, stream>>>(
      hn, W1T, b1, nullptr, nullptr, h1, nullptr, nullptr, nullptr, M, MLPD, DD);
  gemm_bt<1, 64, 128><<<dim3(DD / 128, M / 64), 256, 0, stream>>>(
      h1, W2T, b2, x2, out, nullptr, nullptr, nullptr, nullptr, M, DD, MLPD);
}

// Round 11
// 408.924 us; speedup vs baseline: 1.9267x; 1.0678x over previous
//
#include <hip/hip_runtime.h>
#include <cmath>

// ---------- problem dims (fixed) ----------
#define BB 4
#define PP 1024
#define DD 1024
#define HH 16
#define DHH 64
#define MLPD 4096

typedef __bf16 bf16x8 __attribute__((ext_vector_type(8)));
typedef float f32x4 __attribute__((ext_vector_type(4)));
typedef short short8 __attribute__((ext_vector_type(8)));

__device__ __forceinline__ unsigned short f2b(float f) {
  union { float f; unsigned int u; } x; x.f = f;
  unsigned int r = x.u + 0x7fffu + ((x.u >> 16) & 1u);
  return (unsigned short)(r >> 16);
}

__device__ __forceinline__ f32x4 mfma16(short8 a, short8 b, f32x4 c) {
  return __builtin_amdgcn_mfma_f32_16x16x32_bf16(
      __builtin_bit_cast(bf16x8, a), __builtin_bit_cast(bf16x8, b), c, 0, 0, 0);
}

__device__ __forceinline__ void gload_lds16(const unsigned short* g, unsigned short* l) {
  __builtin_amdgcn_global_load_lds(
      (const __attribute__((address_space(1))) void*)g,
      (__attribute__((address_space(3))) void*)l, 16, 0, 0);
}

// ---------- LayerNorm: fp32 [rows][1024] -> bf16 [rows][1024] ----------
__global__ __launch_bounds__(256)
void ln_kernel(const float* __restrict__ in, const float* __restrict__ g,
               const float* __restrict__ bta, unsigned short* __restrict__ out) {
  int row = blockIdx.x;
  int t = threadIdx.x;
  const float* x = in + (size_t)row * DD;
  float v0 = x[t], v1 = x[t + 256], v2 = x[t + 512], v3 = x[t + 768];
  float s = v0 + v1 + v2 + v3;
  float ss = v0 * v0 + v1 * v1 + v2 * v2 + v3 * v3;
#pragma unroll
  for (int m = 1; m < 64; m <<= 1) { s += __shfl_xor(s, m); ss += __shfl_xor(ss, m); }
  __shared__ float red[8];
  int wave = t >> 6;
  if ((t & 63) == 0) { red[wave] = s; red[4 + wave] = ss; }
  __syncthreads();
  s = red[0] + red[1] + red[2] + red[3];
  ss = red[4] + red[5] + red[6] + red[7];
  float mu = s * (1.f / DD);
  float var = ss * (1.f / DD) - mu * mu;
  float r = rsqrtf(var + 1e-5f);
  unsigned short* o = out + (size_t)row * DD;
  o[t]       = f2b((v0 - mu) * r * g[t]       + bta[t]);
  o[t + 256] = f2b((v1 - mu) * r * g[t + 256] + bta[t + 256]);
  o[t + 512] = f2b((v2 - mu) * r * g[t + 512] + bta[t + 512]);
  o[t + 768] = f2b((v3 - mu) * r * g[t + 768] + bta[t + 768]);
}

// ---------- Transpose+cast: W f32 [K][N] -> Wt bf16 [N][K], 64x64 tiles ----------
__global__ __launch_bounds__(256)
void tcast_kernel(const float* __restrict__ W, unsigned short* __restrict__ Wt,
                  int K, int N) {
  __shared__ float Tl[64][65];
  int k0 = blockIdx.y * 64, n0 = blockIdx.x * 64;
  int t = threadIdx.x;
  int rr = t >> 4, cc = (t & 15) * 4;
#pragma unroll
  for (int p = 0; p < 4; ++p) {
    const float4 v = *(const float4*)&W[(size_t)(k0 + rr + p * 16) * N + n0 + cc];
    Tl[rr + p * 16][cc + 0] = v.x;
    Tl[rr + p * 16][cc + 1] = v.y;
    Tl[rr + p * 16][cc + 2] = v.z;
    Tl[rr + p * 16][cc + 3] = v.w;
  }
  __syncthreads();
  int wr = t >> 3, wc = (t & 7) * 8;
#pragma unroll
  for (int p = 0; p < 2; ++p) {
    int n = wr + p * 32;
    short8 o;
#pragma unroll
    for (int i = 0; i < 8; ++i) o[i] = (short)f2b(Tl[wc + i][n]);
    *(short8*)&Wt[(size_t)(n0 + n) * K + k0 + wc] = o;
  }
}

// ---------- GEMM: C[M,N] = A(bf16,[M,K]) * Bt(bf16,[N][K])^T + bias ----------
// m97 LDS layout + double-buffered prefetch (T3 minimum-2-phase) + XCD swizzle (T1).
// EPI 0: split q/k/v;  EPI 1: fp32 = acc+bias+resid;  EPI 2: bf16 = gelu(acc+bias)
template <int EPI, int BM, int BN>
__global__ __launch_bounds__(256)
void gemm_bt(const unsigned short* __restrict__ A, const unsigned short* __restrict__ Bt,
             const float* __restrict__ bias, const float* __restrict__ resid,
             float* __restrict__ outF, unsigned short* __restrict__ outB,
             unsigned short* __restrict__ outQ, unsigned short* __restrict__ outK,
             unsigned short* __restrict__ outV, int M, int N, int K) {
  constexpr int WM = BM / 2, WN = BN / 2, FM = WM / 16, FN = WN / 16;
  __shared__ unsigned short As[2][BM * 32];
  __shared__ unsigned short Bs[2][BN * 32];
  int t = threadIdx.x;
  int wave = t >> 6, lane = t & 63;
  int wm = wave >> 1, wn = wave & 1;
  int lr = lane & 15, lg = lane >> 4;

  // XCD-aware swizzle: nwg % 8 == 0 for all launches (512/768/1024)
  int nwg = gridDim.x * gridDim.y;
  int bid = blockIdx.y * gridDim.x + blockIdx.x;
  int cpx = nwg >> 3;
  int swz = (bid & 7) * cpx + (bid >> 3);
  int bx = swz % gridDim.x, by = swz / gridDim.x;
  int bm0 = by * BM, bn0 = bx * BN;

  int srow = lane >> 2;          // row within 16-row chunk
  int skof = (lane & 3) * 8;     // k offset (shorts)

  f32x4 acc[FM][FN];
#pragma unroll
  for (int i = 0; i < FM; ++i)
#pragma unroll
    for (int j = 0; j < FN; ++j) acc[i][j] = (f32x4){0.f, 0.f, 0.f, 0.f};

  auto stage = [&](int buf, int k0) {
#pragma unroll
    for (int i = 0; i < BM / 64; ++i) {
      int ch = wave + i * 4;
      gload_lds16(&A[(size_t)(bm0 + ch * 16 + srow) * K + k0 + skof], &As[buf][ch * 512]);
    }
#pragma unroll
    for (int i = 0; i < BN / 64; ++i) {
      int ch = wave + i * 4;
      gload_lds16(&Bt[(size_t)(bn0 + ch * 16 + srow) * K + k0 + skof], &Bs[buf][ch * 512]);
    }
  };

  int nk = K >> 5;
  stage(0, 0);
  __syncthreads();  // drains vmcnt -> buf0 ready
  for (int kt = 0; kt < nk; ++kt) {
    int cur = kt & 1;
    if (kt + 1 < nk) stage(cur ^ 1, (kt + 1) << 5);  // prefetch next tile (async)
    short8 af[FM], bf[FN];
#pragma unroll
    for (int i = 0; i < FM; ++i)
      af[i] = *(const short8*)&As[cur][(wm * WM + i * 16 + lr) * 32 + lg * 8];
#pragma unroll
    for (int i = 0; i < FN; ++i)
      bf[i] = *(const short8*)&Bs[cur][(wn * WN + i * 16 + lr) * 32 + lg * 8];
#pragma unroll
    for (int mi = 0; mi < FM; ++mi)
#pragma unroll
      for (int ni = 0; ni < FN; ++ni) acc[mi][ni] = mfma16(af[mi], bf[ni], acc[mi][ni]);
    __syncthreads();  // drains prefetch loads + protects buf reuse
  }

#pragma unroll
  for (int mi = 0; mi < FM; ++mi)
#pragma unroll
    for (int ni = 0; ni < FN; ++ni) {
      int r0 = bm0 + wm * WM + mi * 16 + lg * 4;
      int c = bn0 + wn * WN + ni * 16 + lr;
      float bval = bias[c];
#pragma unroll
      for (int j = 0; j < 4; ++j) {
        float v = acc[mi][ni][j] + bval;
        int row = r0 + j;
        size_t idx = (size_t)row * N + c;
        if constexpr (EPI == 1) {
          outF[idx] = v + resid[idx];
        } else if constexpr (EPI == 2) {
          outB[idx] = f2b(0.5f * v * (1.f + erff(v * 0.70710678f)));
        } else {  // QKV split
          int which = c >> 10, rem = c & 1023;
          int h = rem >> 6, dh = rem & 63;
          int b = row >> 10, p = row & 1023;
          unsigned short* dst = (which == 0) ? outQ : (which == 1) ? outK : outV;
          dst[(((size_t)b * HH + h) * PP + p) * DHH + dh] = f2b(v);
        }
      }
    }
}

// ---------- Flash attention: q,k,v bf16 [B*H][P][64] -> o bf16 [B*P][1024] ----------
__global__ __launch_bounds__(256)
void attn_kernel(const unsigned short* __restrict__ Qg, const unsigned short* __restrict__ Kg,
                 const unsigned short* __restrict__ Vg, unsigned short* __restrict__ Og) {
  int bh = blockIdx.x;  // b*H + h
  int qb = blockIdx.y;  // q block of 64
  int t = threadIdx.x;
  int wave = t >> 6, lane = t & 63;
  int lr = lane & 15, lg = lane >> 4;

  __shared__ unsigned short Kl[64][72];
  __shared__ unsigned short Vt[64][72];
  __shared__ unsigned short Pl[4][16][72];

  const unsigned short* qrow = Qg + ((size_t)bh * PP + qb * 64 + wave * 16 + lr) * DHH;
  short8 qf0 = *(const short8*)(qrow + lg * 8);
  short8 qf1 = *(const short8*)(qrow + 32 + lg * 8);

  f32x4 zero = {0.f, 0.f, 0.f, 0.f};
  f32x4 accO[4];
#pragma unroll
  for (int i = 0; i < 4; ++i) accO[i] = zero;
  float m_run[4], l_run[4];
#pragma unroll
  for (int j = 0; j < 4; ++j) { m_run[j] = -1e30f; l_run[j] = 0.f; }

  const unsigned short* Kbase = Kg + (size_t)bh * PP * DHH;
  const unsigned short* Vbase = Vg + (size_t)bh * PP * DHH;

  int kvr = t >> 3, chc = (t & 7) * 8;

  for (int kb = 0; kb < PP / 64; ++kb) {
    __syncthreads();
#pragma unroll
    for (int p = 0; p < 2; ++p) {
      int r = kvr + p * 32;
      short8 k8 = *(const short8*)(Kbase + (size_t)(kb * 64 + r) * DHH + chc);
      *(short8*)&Kl[r][chc] = k8;
      short8 v8 = *(const short8*)(Vbase + (size_t)(kb * 64 + r) * DHH + chc);
#pragma unroll
      for (int i = 0; i < 8; ++i) Vt[chc + i][r] = (unsigned short)v8[i];
    }
    __syncthreads();

    f32x4 s[4];
#pragma unroll
    for (int ni = 0; ni < 4; ++ni) {
      s[ni] = zero;
      short8 kf0 = *(const short8*)&Kl[ni * 16 + lr][lg * 8];
      short8 kf1 = *(const short8*)&Kl[ni * 16 + lr][32 + lg * 8];
      s[ni] = mfma16(qf0, kf0, s[ni]);
      s[ni] = mfma16(qf1, kf1, s[ni]);
    }
#pragma unroll
    for (int ni = 0; ni < 4; ++ni)
#pragma unroll
      for (int j = 0; j < 4; ++j) s[ni][j] *= 0.125f;

#pragma unroll
    for (int j = 0; j < 4; ++j) {
      float mt = fmaxf(fmaxf(s[0][j], s[1][j]), fmaxf(s[2][j], s[3][j]));
      mt = fmaxf(mt, __shfl_xor(mt, 1));
      mt = fmaxf(mt, __shfl_xor(mt, 2));
      mt = fmaxf(mt, __shfl_xor(mt, 4));
      mt = fmaxf(mt, __shfl_xor(mt, 8));
      float mn = fmaxf(m_run[j], mt);
      float sc = __expf(m_run[j] - mn);
      m_run[j] = mn;
      float ps = 0.f;
#pragma unroll
      for (int ni = 0; ni < 4; ++ni) {
        float p = __expf(s[ni][j] - mn);
        s[ni][j] = p;
        ps += p;
      }
      l_run[j] = l_run[j] * sc + ps;
#pragma unroll
      for (int ni = 0; ni < 4; ++ni) accO[ni][j] *= sc;
    }

#pragma unroll
    for (int ni = 0; ni < 4; ++ni)
#pragma unroll
      for (int j = 0; j < 4; ++j) Pl[wave][lg * 4 + j][ni * 16 + lr] = f2b(s[ni][j]);
    __syncthreads();

    short8 pf0 = *(const short8*)&Pl[wave][lr][lg * 8];
    short8 pf1 = *(const short8*)&Pl[wave][lr][32 + lg * 8];
#pragma unroll
    for (int ni = 0; ni < 4; ++ni) {
      short8 vf0 = *(const short8*)&Vt[ni * 16 + lr][lg * 8];
      short8 vf1 = *(const short8*)&Vt[ni * 16 + lr][32 + lg * 8];
      accO[ni] = mfma16(pf0, vf0, accO[ni]);
      accO[ni] = mfma16(pf1, vf1, accO[ni]);
    }
  }

#pragma unroll
  for (int j = 0; j < 4; ++j) {
    float l = l_run[j];
    l += __shfl_xor(l, 1);
    l += __shfl_xor(l, 2);
    l += __shfl_xor(l, 4);
    l += __shfl_xor(l, 8);
    float inv = 1.f / l;
#pragma unroll
    for (int ni = 0; ni < 4; ++ni) accO[ni][j] *= inv;
  }
  size_t token = (size_t)(bh >> 4) * PP + qb * 64 + wave * 16;
  int h = bh & 15;
#pragma unroll
  for (int ni = 0; ni < 4; ++ni)
#pragma unroll
    for (int j = 0; j < 4; ++j)
      Og[(token + lg * 4 + j) * DD + h * DHH + ni * 16 + lr] = f2b(accO[ni][j]);
}

// ---------- launch ----------
extern "C" void kernel_launch(void* const* d_in, const int* in_sizes, int n_in,
                              void* d_out, int out_size, void* d_ws, size_t ws_size,
                              hipStream_t stream) {
  const float* x    = (const float*)d_in[0];
  const float* ln1g = (const float*)d_in[1];
  const float* ln1b = (const float*)d_in[2];
  const float* Wqkv = (const float*)d_in[3];
  const float* bqkv = (const float*)d_in[4];
  const float* Wo   = (const float*)d_in[5];
  const float* bo   = (const float*)d_in[6];
  const float* ln2g = (const float*)d_in[7];
  const float* ln2b = (const float*)d_in[8];
  const float* W1   = (const float*)d_in[9];
  const float* b1   = (const float*)d_in[10];
  const float* W2   = (const float*)d_in[11];
  const float* b2   = (const float*)d_in[12];
  float* out = (float*)d_out;

  char* ws = (char*)d_ws;
  // layout (MB): [0,8) xn then hn  | [8,40) q/k/v/ob then h1 | [40,56) x2 |
  //              [56,62) WqkvT | [62,64) WoT | [64,72) W1T | [72,80) W2T
  unsigned short* xn   = (unsigned short*)(ws);
  unsigned short* hn   = (unsigned short*)(ws);                  // alias: xn dead after QKV
  unsigned short* qb   = (unsigned short*)(ws + (8ull << 20));
  unsigned short* kb   = (unsigned short*)(ws + (16ull << 20));
  unsigned short* vb   = (unsigned short*)(ws + (24ull << 20));
  unsigned short* ob   = (unsigned short*)(ws + (32ull << 20));
  unsigned short* h1   = (unsigned short*)(ws + (8ull << 20));   // alias: qkv+ob dead after proj
  float*          x2   = (float*)(ws + (40ull << 20));
  unsigned short* WqkvT= (unsigned short*)(ws + (56ull << 20));
  unsigned short* WoT  = (unsigned short*)(ws + (62ull << 20));
  unsigned short* W1T  = (unsigned short*)(ws + (64ull << 20));
  unsigned short* W2T  = (unsigned short*)(ws + (72ull << 20));

  const int M = BB * PP;  // 4096

  // one-time weight precast+transpose
  tcast_kernel<<<dim3(3 * DD / 64, DD / 64), 256, 0, stream>>>(Wqkv, WqkvT, DD, 3 * DD);
  tcast_kernel<<<dim3(DD / 64, DD / 64), 256, 0, stream>>>(Wo, WoT, DD, DD);
  tcast_kernel<<<dim3(MLPD / 64, DD / 64), 256, 0, stream>>>(W1, W1T, DD, MLPD);
  tcast_kernel<<<dim3(DD / 64, MLPD / 64), 256, 0, stream>>>(W2, W2T, MLPD, DD);

  ln_kernel<<<M, 256, 0, stream>>>(x, ln1g, ln1b, xn);
  gemm_bt<0, 128, 128><<<dim3(3 * DD / 128, M / 128), 256, 0, stream>>>(
      xn, WqkvT, bqkv, nullptr, nullptr, nullptr, qb, kb, vb, M, 3 * DD, DD);
  attn_kernel<<<dim3(BB * HH, PP / 64), 256, 0, stream>>>(qb, kb, vb, ob);
  gemm_bt<1, 64, 128><<<dim3(DD / 128, M / 64), 256, 0, stream>>>(
      ob, WoT, bo, x, x2, nullptr, nullptr, nullptr, nullptr, M, DD, DD);
  ln_kernel<<<M, 256, 0, stream>>>(x2, ln2g, ln2b, hn);
  gemm_bt<2, 128, 128><<<dim3(MLPD / 128, M / 128), 256, 0, stream>>>(
      hn, W1T, b1, nullptr, nullptr, h1, nullptr, nullptr, nullptr, M, MLPD, DD);
  gemm_bt<1, 64, 128><<<dim3(DD / 128, M / 64), 256, 0, stream>>>(
      h1, W2T, b2, x2, out, nullptr, nullptr, nullptr, nullptr, M, DD, MLPD);
}